// Round 1
// baseline (857.920 us; speedup 1.0000x reference)
//
#include <hip/hip_runtime.h>

#define BS 32
#define LQ 300
#define CDIM 256
#define HEADS 8
#define HD 32
#define NLEVELS 3
#define NPOINTS 4
#define LV 8400   // 80*80 + 40*40 + 20*20

__device__ __forceinline__ unsigned short f2bf(float f) {
    union { float f; unsigned u; } v; v.f = f;
    unsigned r = v.u + 0x7FFFu + ((v.u >> 16) & 1u);
    return (unsigned short)(r >> 16);
}
__device__ __forceinline__ float bf2f(unsigned short u) {
    union { unsigned u; float f; } v; v.u = ((unsigned)u) << 16;
    return v.f;
}

// ---------------------------------------------------------------------------
// Kernel A: v = value @ Wv + bv   -> bf16 [BS*LV, 256]
// 16 rows x 256 cols per block; each thread computes a 4x4 tile.
// ---------------------------------------------------------------------------
__global__ __launch_bounds__(256) void proj_value_kernel(
    const float* __restrict__ value, const float* __restrict__ Wv,
    const float* __restrict__ bv, unsigned short* __restrict__ vout)
{
    __shared__ float a[16 * 256];
    const int tid = threadIdx.x;
    const long row0 = (long)blockIdx.x * 16;

    const float4* src = (const float4*)(value + row0 * CDIM);
    float4* af4 = (float4*)a;
#pragma unroll
    for (int j = 0; j < 4; ++j) af4[tid + j * 256] = src[tid + j * 256];
    __syncthreads();

    const int r0 = (tid >> 6) << 2;   // 0,4,8,12
    const int c0 = (tid & 63) << 2;   // 0..252 step 4
    float acc[4][4] = {};

    for (int k = 0; k < CDIM; k += 4) {
        const float4 w0 = *(const float4*)&Wv[(k + 0) * CDIM + c0];
        const float4 w1 = *(const float4*)&Wv[(k + 1) * CDIM + c0];
        const float4 w2 = *(const float4*)&Wv[(k + 2) * CDIM + c0];
        const float4 w3 = *(const float4*)&Wv[(k + 3) * CDIM + c0];
#pragma unroll
        for (int r = 0; r < 4; ++r) {
            const float4 av = *(const float4*)&a[(r0 + r) * CDIM + k];
            acc[r][0] = fmaf(av.x, w0.x, fmaf(av.y, w1.x, fmaf(av.z, w2.x, fmaf(av.w, w3.x, acc[r][0]))));
            acc[r][1] = fmaf(av.x, w0.y, fmaf(av.y, w1.y, fmaf(av.z, w2.y, fmaf(av.w, w3.y, acc[r][1]))));
            acc[r][2] = fmaf(av.x, w0.z, fmaf(av.y, w1.z, fmaf(av.z, w2.z, fmaf(av.w, w3.z, acc[r][2]))));
            acc[r][3] = fmaf(av.x, w0.w, fmaf(av.y, w1.w, fmaf(av.z, w2.w, fmaf(av.w, w3.w, acc[r][3]))));
        }
    }

    const float4 bb = *(const float4*)&bv[c0];
#pragma unroll
    for (int r = 0; r < 4; ++r) {
        ushort4 o;
        o.x = f2bf(acc[r][0] + bb.x);
        o.y = f2bf(acc[r][1] + bb.y);
        o.z = f2bf(acc[r][2] + bb.z);
        o.w = f2bf(acc[r][3] + bb.w);
        *(ushort4*)&vout[(row0 + r0 + r) * CDIM + c0] = o;
    }
}

// ---------------------------------------------------------------------------
// Kernel B: fused offsets + attention logits + softmax + bilinear sampling.
// One block per (b, q); 256 threads.
// ---------------------------------------------------------------------------
__global__ __launch_bounds__(256) void fused_sample_kernel(
    const float* __restrict__ query, const float* __restrict__ refpts,
    const unsigned short* __restrict__ v,
    const float* __restrict__ Woff, const float* __restrict__ boff,
    const float* __restrict__ Watt, const float* __restrict__ batt,
    float* __restrict__ mid)
{
    __shared__ float qs[256];
    __shared__ float off_s[192];
    __shared__ float aw_s[96];
    __shared__ float px_s[96];
    __shared__ float py_s[96];

    const int tid = threadIdx.x;
    const int b = blockIdx.x / LQ;
    const int q = blockIdx.x % LQ;
    const long bq = (long)b * LQ + q;

    qs[tid] = query[bq * CDIM + tid];
    __syncthreads();

    if (tid < 192) {
        float acc = boff[tid];
        for (int k = 0; k < CDIM; ++k) acc = fmaf(qs[k], Woff[k * 192 + tid], acc);
        off_s[tid] = acc;
    } else {
        const int j = tid - 192;
        float acc = batt[j];
        for (int k = 0; k < CDIM; ++k) acc = fmaf(qs[k], Watt[k * 96 + j], acc);
        aw_s[j] = acc;
    }
    if (tid < 32) {
        const int j = 64 + tid;
        float acc = batt[j];
        for (int k = 0; k < CDIM; ++k) acc = fmaf(qs[k], Watt[k * 96 + j], acc);
        aw_s[j] = acc;
    }
    __syncthreads();

    // softmax over 12 per head (threads 0..7), locations (threads 128..223)
    if (tid < 8) {
        float m = -1e30f;
#pragma unroll
        for (int i = 0; i < 12; ++i) m = fmaxf(m, aw_s[tid * 12 + i]);
        float e[12];
        float s = 0.f;
#pragma unroll
        for (int i = 0; i < 12; ++i) { e[i] = __expf(aw_s[tid * 12 + i] - m); s += e[i]; }
        const float inv = 1.f / s;
#pragma unroll
        for (int i = 0; i < 12; ++i) aw_s[tid * 12 + i] = e[i] * inv;
    }
    if (tid >= 128 && tid < 224) {
        const int t = tid - 128;
        const int h = t / 12, idx = t % 12, l = idx >> 2, p = idx & 3;
        const float* rp = refpts + (bq * NLEVELS + l) * 4;
        const float rx = rp[0], ry = rp[1], rw = rp[2], rh = rp[3];
        const float ox = off_s[((h * NLEVELS + l) * NPOINTS + p) * 2 + 0];
        const float oy = off_s[((h * NLEVELS + l) * NPOINTS + p) * 2 + 1];
        const float lx = rx + ox * 0.125f * rw;
        const float ly = ry + oy * 0.125f * rh;
        const int Wl = (l == 0) ? 80 : (l == 1) ? 40 : 20;
        px_s[t] = lx * (float)Wl - 0.5f;
        py_s[t] = ly * (float)Wl - 0.5f;
    }
    __syncthreads();

    // sampling: thread = (h, d)
    const int h = tid >> 5, d = tid & 31;
    const unsigned short* vb = v + ((size_t)b * LV) * CDIM + h * HD + d;
    float acc = 0.f;
    int start = 0;
#pragma unroll
    for (int l = 0; l < NLEVELS; ++l) {
        const int Wl = (l == 0) ? 80 : (l == 1) ? 40 : 20;
        const int Hl = Wl;
#pragma unroll
        for (int p = 0; p < NPOINTS; ++p) {
            const int i = h * 12 + l * 4 + p;
            const float px = px_s[i], py = py_s[i], aw = aw_s[i];
            const float fx = floorf(px), fy = floorf(py);
            const int x0 = (int)fx, y0 = (int)fy;
            const float wx1 = px - fx, wy1 = py - fy;
            const float wx0 = 1.f - wx1, wy0 = 1.f - wy1;
            const bool x0v = (x0 >= 0) & (x0 < Wl);
            const bool x1v = (x0 >= -1) & (x0 < Wl - 1);
            float s = 0.f;
            if (y0 >= 0 && y0 < Hl) {
                const unsigned short* rowp = vb + (size_t)(start + y0 * Wl) * CDIM;
                if (x0v) s = fmaf(wx0 * wy0, bf2f(rowp[(size_t)x0 * CDIM]), s);
                if (x1v) s = fmaf(wx1 * wy0, bf2f(rowp[(size_t)(x0 + 1) * CDIM]), s);
            }
            if (y0 >= -1 && y0 < Hl - 1) {
                const unsigned short* rowp = vb + (size_t)(start + (y0 + 1) * Wl) * CDIM;
                if (x0v) s = fmaf(wx0 * wy1, bf2f(rowp[(size_t)x0 * CDIM]), s);
                if (x1v) s = fmaf(wx1 * wy1, bf2f(rowp[(size_t)(x0 + 1) * CDIM]), s);
            }
            acc = fmaf(aw, s, acc);
        }
        start += Wl * Hl;
    }
    mid[bq * CDIM + tid] = acc;
}

// ---------------------------------------------------------------------------
// Kernel C: out = mid @ Wout + bout  (f32)
// ---------------------------------------------------------------------------
__global__ __launch_bounds__(256) void out_gemm_kernel(
    const float* __restrict__ mid, const float* __restrict__ Wout,
    const float* __restrict__ bout, float* __restrict__ out)
{
    __shared__ float a[16 * 256];
    const int tid = threadIdx.x;
    const long row0 = (long)blockIdx.x * 16;

    const float4* src = (const float4*)(mid + row0 * CDIM);
    float4* af4 = (float4*)a;
#pragma unroll
    for (int j = 0; j < 4; ++j) af4[tid + j * 256] = src[tid + j * 256];
    __syncthreads();

    const int r0 = (tid >> 6) << 2;
    const int c0 = (tid & 63) << 2;
    float acc[4][4] = {};

    for (int k = 0; k < CDIM; k += 4) {
        const float4 w0 = *(const float4*)&Wout[(k + 0) * CDIM + c0];
        const float4 w1 = *(const float4*)&Wout[(k + 1) * CDIM + c0];
        const float4 w2 = *(const float4*)&Wout[(k + 2) * CDIM + c0];
        const float4 w3 = *(const float4*)&Wout[(k + 3) * CDIM + c0];
#pragma unroll
        for (int r = 0; r < 4; ++r) {
            const float4 av = *(const float4*)&a[(r0 + r) * CDIM + k];
            acc[r][0] = fmaf(av.x, w0.x, fmaf(av.y, w1.x, fmaf(av.z, w2.x, fmaf(av.w, w3.x, acc[r][0]))));
            acc[r][1] = fmaf(av.x, w0.y, fmaf(av.y, w1.y, fmaf(av.z, w2.y, fmaf(av.w, w3.y, acc[r][1]))));
            acc[r][2] = fmaf(av.x, w0.z, fmaf(av.y, w1.z, fmaf(av.z, w2.z, fmaf(av.w, w3.z, acc[r][2]))));
            acc[r][3] = fmaf(av.x, w0.w, fmaf(av.y, w1.w, fmaf(av.z, w2.w, fmaf(av.w, w3.w, acc[r][3]))));
        }
    }

    const float4 bb = *(const float4*)&bout[c0];
#pragma unroll
    for (int r = 0; r < 4; ++r) {
        float4 o;
        o.x = acc[r][0] + bb.x;
        o.y = acc[r][1] + bb.y;
        o.z = acc[r][2] + bb.z;
        o.w = acc[r][3] + bb.w;
        *(float4*)&out[(row0 + r0 + r) * CDIM + c0] = o;
    }
}

extern "C" void kernel_launch(void* const* d_in, const int* in_sizes, int n_in,
                              void* d_out, int out_size, void* d_ws, size_t ws_size,
                              hipStream_t stream) {
    const float* query = (const float*)d_in[0];
    const float* refp  = (const float*)d_in[1];
    const float* value = (const float*)d_in[2];
    const float* Wv    = (const float*)d_in[3];
    const float* bv    = (const float*)d_in[4];
    const float* Woff  = (const float*)d_in[5];
    const float* boff  = (const float*)d_in[6];
    const float* Watt  = (const float*)d_in[7];
    const float* batt  = (const float*)d_in[8];
    const float* Wout  = (const float*)d_in[9];
    const float* bout  = (const float*)d_in[10];
    float* out = (float*)d_out;

    unsigned short* v = (unsigned short*)d_ws;                       // bf16 projected value
    const size_t voff = (size_t)BS * LV * CDIM * sizeof(unsigned short); // ~137.6 MB
    float* mid = (float*)((char*)d_ws + voff);                       // (BS*LQ, 256) f32

    proj_value_kernel<<<(BS * LV) / 16, 256, 0, stream>>>(value, Wv, bv, v);
    fused_sample_kernel<<<BS * LQ, 256, 0, stream>>>(query, refp, v, Woff, boff, Watt, batt, mid);
    out_gemm_kernel<<<(BS * LQ) / 16, 256, 0, stream>>>(mid, Wout, bout, out);
}

// Round 2
// 397.806 us; speedup vs baseline: 2.1566x; 2.1566x over previous
//
#include <hip/hip_runtime.h>

#define BS 32
#define LQ 300
#define CDIM 256
#define HEADS 8
#define HD 32
#define NLEVELS 3
#define NPOINTS 4
#define LV 8400   // 80*80 + 40*40 + 20*20

typedef __attribute__((ext_vector_type(4))) float f32x4;
typedef __attribute__((ext_vector_type(8))) short short8;
typedef __attribute__((ext_vector_type(8))) unsigned short u16x8;

__device__ __forceinline__ unsigned short f2bf(float f) {
    union { float f; unsigned u; } v; v.f = f;
    unsigned r = v.u + 0x7FFFu + ((v.u >> 16) & 1u);
    return (unsigned short)(r >> 16);
}
__device__ __forceinline__ float bf2f(unsigned short u) {
    union { unsigned u; float f; } v; v.u = ((unsigned)u) << 16;
    return v.f;
}

// ---------------------------------------------------------------------------
// Kernel W: WvT[n][k] = bf16(Wv[k][n])   (256x256)
// ---------------------------------------------------------------------------
__global__ void transpose_w_kernel(const float* __restrict__ Wv,
                                   unsigned short* __restrict__ WvT)
{
    const int n = blockIdx.x;
    const int k = threadIdx.x;
    WvT[n * 256 + k] = f2bf(Wv[k * 256 + n]);
}

// ---------------------------------------------------------------------------
// Kernel A: v = bf16( value @ Wv + bv )  via MFMA.
// BM=128, BN=256 (full), BK=32. 256 threads = 4 waves (2x2), wave tile 64x128.
// A reg-staged f32->bf16 into padded LDS; B (WvT) reg-staged bf16.
// ---------------------------------------------------------------------------
#define BM 128
#define BK 32
#define APAD 40   // bf16 elements per LDS row (stride 80B: 2-way bank alias = free)
#define BPAD 40

__global__ __launch_bounds__(256) void proj_value_mfma(
    const float* __restrict__ value, const unsigned short* __restrict__ WvT,
    const float* __restrict__ bv, unsigned short* __restrict__ vout)
{
    __shared__ unsigned short lds_a[2][BM * APAD];
    __shared__ unsigned short lds_b[2][256 * BPAD];

    const int tid = threadIdx.x;
    const int lane = tid & 63;
    const int wave = tid >> 6;
    const int wm = wave >> 1;          // m offset 64*wm
    const int wn = wave & 1;           // n offset 128*wn
    const long row0 = (long)blockIdx.x * BM;

    // A staging: thread -> row = tid/2 (0..127), k0 = (tid&1)*16
    const int ar = tid >> 1;
    const int ak = (tid & 1) * 16;
    const float* aptr = value + (row0 + ar) * CDIM + ak;
    // B staging: thread -> n-row tid, 32 bf16 per K-tile
    const unsigned short* bptr = WvT + (size_t)tid * CDIM;

    f32x4 arg[4];
    u16x8 brg[4];

    auto load_tile = [&](int kb) {
        const float* p = aptr + kb;
        arg[0] = *(const f32x4*)(p);
        arg[1] = *(const f32x4*)(p + 4);
        arg[2] = *(const f32x4*)(p + 8);
        arg[3] = *(const f32x4*)(p + 12);
        const u16x8* q = (const u16x8*)(bptr + kb);
        brg[0] = q[0]; brg[1] = q[1]; brg[2] = q[2]; brg[3] = q[3];
    };
    auto write_tile = [&](int buf) {
        u16x8 t0, t1;
#pragma unroll
        for (int i = 0; i < 4; ++i) {
            t0[i]     = f2bf(arg[0][i]);
            t0[i + 4] = f2bf(arg[1][i]);
            t1[i]     = f2bf(arg[2][i]);
            t1[i + 4] = f2bf(arg[3][i]);
        }
        u16x8* wa = (u16x8*)&lds_a[buf][ar * APAD + ak];
        wa[0] = t0; wa[1] = t1;
        u16x8* wb = (u16x8*)&lds_b[buf][tid * BPAD];
        wb[0] = brg[0]; wb[1] = brg[1]; wb[2] = brg[2]; wb[3] = brg[3];
    };

    f32x4 acc[4][8] = {};
    const int la = lane & 15;
    const int lg = lane >> 4;

    load_tile(0);
    write_tile(0);
    __syncthreads();
    int cur = 0;

    for (int t = 0; t < CDIM / BK; ++t) {
        if (t + 1 < CDIM / BK) load_tile((t + 1) * BK);

        const unsigned short* pa = &lds_a[cur][(wm * 64 + la) * APAD + lg * 8];
        const unsigned short* pb = &lds_b[cur][(wn * 128 + la) * BPAD + lg * 8];
        short8 af[4];
#pragma unroll
        for (int mi = 0; mi < 4; ++mi)
            af[mi] = *(const short8*)(pa + mi * 16 * APAD);
#pragma unroll
        for (int ni = 0; ni < 8; ++ni) {
            const short8 bf = *(const short8*)(pb + ni * 16 * BPAD);
#pragma unroll
            for (int mi = 0; mi < 4; ++mi)
                acc[mi][ni] = __builtin_amdgcn_mfma_f32_16x16x32_bf16(af[mi], bf, acc[mi][ni], 0, 0, 0);
        }

        if (t + 1 < CDIM / BK) write_tile(cur ^ 1);
        __syncthreads();
        cur ^= 1;
    }

    // epilogue: add bias, convert, store bf16
    float bvr[8];
#pragma unroll
    for (int ni = 0; ni < 8; ++ni) bvr[ni] = bv[wn * 128 + ni * 16 + la];
#pragma unroll
    for (int mi = 0; mi < 4; ++mi) {
#pragma unroll
        for (int ni = 0; ni < 8; ++ni) {
            const int col = wn * 128 + ni * 16 + la;
#pragma unroll
            for (int j = 0; j < 4; ++j) {
                const long r = row0 + wm * 64 + mi * 16 + lg * 4 + j;
                vout[r * CDIM + col] = f2bf(acc[mi][ni][j] + bvr[ni]);
            }
        }
    }
}

// ---------------------------------------------------------------------------
// Kernel B: fused offsets + attention logits + softmax + bilinear sampling.
// One block per (b, q); 256 threads.
// ---------------------------------------------------------------------------
__global__ __launch_bounds__(256) void fused_sample_kernel(
    const float* __restrict__ query, const float* __restrict__ refpts,
    const unsigned short* __restrict__ v,
    const float* __restrict__ Woff, const float* __restrict__ boff,
    const float* __restrict__ Watt, const float* __restrict__ batt,
    float* __restrict__ mid)
{
    __shared__ float qs[256];
    __shared__ float off_s[192];
    __shared__ float aw_s[96];
    __shared__ float px_s[96];
    __shared__ float py_s[96];

    const int tid = threadIdx.x;
    const int b = blockIdx.x / LQ;
    const int q = blockIdx.x % LQ;
    const long bq = (long)b * LQ + q;

    qs[tid] = query[bq * CDIM + tid];
    __syncthreads();

    if (tid < 192) {
        float acc = boff[tid];
        for (int k = 0; k < CDIM; ++k) acc = fmaf(qs[k], Woff[k * 192 + tid], acc);
        off_s[tid] = acc;
    } else {
        const int j = tid - 192;
        float acc = batt[j];
        for (int k = 0; k < CDIM; ++k) acc = fmaf(qs[k], Watt[k * 96 + j], acc);
        aw_s[j] = acc;
    }
    if (tid < 32) {
        const int j = 64 + tid;
        float acc = batt[j];
        for (int k = 0; k < CDIM; ++k) acc = fmaf(qs[k], Watt[k * 96 + j], acc);
        aw_s[j] = acc;
    }
    __syncthreads();

    if (tid < 8) {
        float m = -1e30f;
#pragma unroll
        for (int i = 0; i < 12; ++i) m = fmaxf(m, aw_s[tid * 12 + i]);
        float e[12];
        float s = 0.f;
#pragma unroll
        for (int i = 0; i < 12; ++i) { e[i] = __expf(aw_s[tid * 12 + i] - m); s += e[i]; }
        const float inv = 1.f / s;
#pragma unroll
        for (int i = 0; i < 12; ++i) aw_s[tid * 12 + i] = e[i] * inv;
    }
    if (tid >= 128 && tid < 224) {
        const int t = tid - 128;
        const int h = t / 12, idx = t % 12, l = idx >> 2, p = idx & 3;
        const float* rp = refpts + (bq * NLEVELS + l) * 4;
        const float rx = rp[0], ry = rp[1], rw = rp[2], rh = rp[3];
        const float ox = off_s[((h * NLEVELS + l) * NPOINTS + p) * 2 + 0];
        const float oy = off_s[((h * NLEVELS + l) * NPOINTS + p) * 2 + 1];
        const float lx = rx + ox * 0.125f * rw;
        const float ly = ry + oy * 0.125f * rh;
        const int Wl = (l == 0) ? 80 : (l == 1) ? 40 : 20;
        px_s[t] = lx * (float)Wl - 0.5f;
        py_s[t] = ly * (float)Wl - 0.5f;
    }
    __syncthreads();

    const int h = tid >> 5, d = tid & 31;
    const unsigned short* vb = v + ((size_t)b * LV) * CDIM + h * HD + d;
    float acc = 0.f;
    int start = 0;
#pragma unroll
    for (int l = 0; l < NLEVELS; ++l) {
        const int Wl = (l == 0) ? 80 : (l == 1) ? 40 : 20;
        const int Hl = Wl;
#pragma unroll
        for (int p = 0; p < NPOINTS; ++p) {
            const int i = h * 12 + l * 4 + p;
            const float px = px_s[i], py = py_s[i], aw = aw_s[i];
            const float fx = floorf(px), fy = floorf(py);
            const int x0 = (int)fx, y0 = (int)fy;
            const float wx1 = px - fx, wy1 = py - fy;
            const float wx0 = 1.f - wx1, wy0 = 1.f - wy1;
            const bool x0v = (x0 >= 0) & (x0 < Wl);
            const bool x1v = (x0 >= -1) & (x0 < Wl - 1);
            float s = 0.f;
            if (y0 >= 0 && y0 < Hl) {
                const unsigned short* rowp = vb + (size_t)(start + y0 * Wl) * CDIM;
                if (x0v) s = fmaf(wx0 * wy0, bf2f(rowp[(size_t)x0 * CDIM]), s);
                if (x1v) s = fmaf(wx1 * wy0, bf2f(rowp[(size_t)(x0 + 1) * CDIM]), s);
            }
            if (y0 >= -1 && y0 < Hl - 1) {
                const unsigned short* rowp = vb + (size_t)(start + (y0 + 1) * Wl) * CDIM;
                if (x0v) s = fmaf(wx0 * wy1, bf2f(rowp[(size_t)x0 * CDIM]), s);
                if (x1v) s = fmaf(wx1 * wy1, bf2f(rowp[(size_t)(x0 + 1) * CDIM]), s);
            }
            acc = fmaf(aw, s, acc);
        }
        start += Wl * Hl;
    }
    mid[bq * CDIM + tid] = acc;
}

// ---------------------------------------------------------------------------
// Kernel C: out = mid @ Wout + bout  (f32)
// ---------------------------------------------------------------------------
__global__ __launch_bounds__(256) void out_gemm_kernel(
    const float* __restrict__ mid, const float* __restrict__ Wout,
    const float* __restrict__ bout, float* __restrict__ out)
{
    __shared__ float a[16 * 256];
    const int tid = threadIdx.x;
    const long row0 = (long)blockIdx.x * 16;

    const float4* src = (const float4*)(mid + row0 * CDIM);
    float4* af4 = (float4*)a;
#pragma unroll
    for (int j = 0; j < 4; ++j) af4[tid + j * 256] = src[tid + j * 256];
    __syncthreads();

    const int r0 = (tid >> 6) << 2;
    const int c0 = (tid & 63) << 2;
    float acc[4][4] = {};

    for (int k = 0; k < CDIM; k += 4) {
        const float4 w0 = *(const float4*)&Wout[(k + 0) * CDIM + c0];
        const float4 w1 = *(const float4*)&Wout[(k + 1) * CDIM + c0];
        const float4 w2 = *(const float4*)&Wout[(k + 2) * CDIM + c0];
        const float4 w3 = *(const float4*)&Wout[(k + 3) * CDIM + c0];
#pragma unroll
        for (int r = 0; r < 4; ++r) {
            const float4 av = *(const float4*)&a[(r0 + r) * CDIM + k];
            acc[r][0] = fmaf(av.x, w0.x, fmaf(av.y, w1.x, fmaf(av.z, w2.x, fmaf(av.w, w3.x, acc[r][0]))));
            acc[r][1] = fmaf(av.x, w0.y, fmaf(av.y, w1.y, fmaf(av.z, w2.y, fmaf(av.w, w3.y, acc[r][1]))));
            acc[r][2] = fmaf(av.x, w0.z, fmaf(av.y, w1.z, fmaf(av.z, w2.z, fmaf(av.w, w3.z, acc[r][2]))));
            acc[r][3] = fmaf(av.x, w0.w, fmaf(av.y, w1.w, fmaf(av.z, w2.w, fmaf(av.w, w3.w, acc[r][3]))));
        }
    }

    const float4 bb = *(const float4*)&bout[c0];
#pragma unroll
    for (int r = 0; r < 4; ++r) {
        float4 o;
        o.x = acc[r][0] + bb.x;
        o.y = acc[r][1] + bb.y;
        o.z = acc[r][2] + bb.z;
        o.w = acc[r][3] + bb.w;
        *(float4*)&out[(row0 + r0 + r) * CDIM + c0] = o;
    }
}

extern "C" void kernel_launch(void* const* d_in, const int* in_sizes, int n_in,
                              void* d_out, int out_size, void* d_ws, size_t ws_size,
                              hipStream_t stream) {
    const float* query = (const float*)d_in[0];
    const float* refp  = (const float*)d_in[1];
    const float* value = (const float*)d_in[2];
    const float* Wv    = (const float*)d_in[3];
    const float* bv    = (const float*)d_in[4];
    const float* Woff  = (const float*)d_in[5];
    const float* boff  = (const float*)d_in[6];
    const float* Watt  = (const float*)d_in[7];
    const float* batt  = (const float*)d_in[8];
    const float* Wout  = (const float*)d_in[9];
    const float* bout  = (const float*)d_in[10];
    float* out = (float*)d_out;

    unsigned short* v = (unsigned short*)d_ws;                           // bf16 [BS*LV, 256]
    const size_t voff = (size_t)BS * LV * CDIM * sizeof(unsigned short); // ~137.6 MB
    float* mid = (float*)((char*)d_ws + voff);                           // f32 [BS*LQ, 256]
    const size_t moff = voff + (size_t)BS * LQ * CDIM * sizeof(float);
    unsigned short* WvT = (unsigned short*)((char*)d_ws + moff);         // bf16 [256][256]

    transpose_w_kernel<<<256, 256, 0, stream>>>(Wv, WvT);
    proj_value_mfma<<<(BS * LV) / BM, 256, 0, stream>>>(value, WvT, bv, v);
    fused_sample_kernel<<<BS * LQ, 256, 0, stream>>>(query, refp, v, Woff, boff, Watt, batt, mid);
    out_gemm_kernel<<<(BS * LQ) / 16, 256, 0, stream>>>(mid, Wout, bout, out);
}

// Round 3
// 210.301 us; speedup vs baseline: 4.0795x; 1.8916x over previous
//
#include <hip/hip_runtime.h>

#define BS 32
#define LQ 300
#define CDIM 256
#define HEADS 8
#define HD 32
#define NLEVELS 3
#define NPOINTS 4
#define LV 8400   // 80*80 + 40*40 + 20*20
#define NOA 288   // 192 offset cols + 96 att cols

typedef __attribute__((ext_vector_type(4))) float f32x4;
typedef __attribute__((ext_vector_type(8))) short short8;
typedef __attribute__((ext_vector_type(8))) unsigned short u16x8;
typedef __attribute__((ext_vector_type(4))) unsigned short u16x4;

__device__ __forceinline__ unsigned short f2bf(float f) {
    union { float f; unsigned u; } v; v.f = f;
    unsigned r = v.u + 0x7FFFu + ((v.u >> 16) & 1u);
    return (unsigned short)(r >> 16);
}
__device__ __forceinline__ float bf2f(unsigned short u) {
    union { unsigned u; float f; } v; v.u = ((unsigned)u) << 16;
    return v.f;
}

// ---------------------------------------------------------------------------
// Prep: WT[n][k] = bf16(W[k][n])  (256x256, generic)
// ---------------------------------------------------------------------------
__global__ void transpose_w_kernel(const float* __restrict__ W,
                                   unsigned short* __restrict__ WT)
{
    const int n = blockIdx.x;
    const int k = threadIdx.x;
    WT[n * 256 + k] = f2bf(W[k * 256 + n]);
}

// Prep: WoaT[n][k]: n<192 -> Woff[k][n], else Watt[k][n-192]
__global__ void prep_woat_kernel(const float* __restrict__ Woff,
                                 const float* __restrict__ Watt,
                                 unsigned short* __restrict__ WoaT)
{
    const int n = blockIdx.x;
    const int k = threadIdx.x;
    const float w = (n < 192) ? Woff[k * 192 + n] : Watt[k * 96 + (n - 192)];
    WoaT[n * 256 + k] = f2bf(w);
}

// ---------------------------------------------------------------------------
// Kernel A: v = bf16( value @ Wv + bv )  via MFMA. (unchanged from round 2)
// BM=128, BN=256, BK=32, 4 waves (2x2), wave tile 64x128.
// ---------------------------------------------------------------------------
#define BM 128
#define BK 32
#define APAD 40
#define BPAD 40

__global__ __launch_bounds__(256) void proj_value_mfma(
    const float* __restrict__ value, const unsigned short* __restrict__ WvT,
    const float* __restrict__ bv, unsigned short* __restrict__ vout)
{
    __shared__ unsigned short lds_a[2][BM * APAD];
    __shared__ unsigned short lds_b[2][256 * BPAD];

    const int tid = threadIdx.x;
    const int lane = tid & 63;
    const int wave = tid >> 6;
    const int wm = wave >> 1;
    const int wn = wave & 1;
    const long row0 = (long)blockIdx.x * BM;

    const int ar = tid >> 1;
    const int ak = (tid & 1) * 16;
    const float* aptr = value + (row0 + ar) * CDIM + ak;
    const unsigned short* bptr = WvT + (size_t)tid * CDIM;

    f32x4 arg[4];
    u16x8 brg[4];

    auto load_tile = [&](int kb) {
        const float* p = aptr + kb;
        arg[0] = *(const f32x4*)(p);
        arg[1] = *(const f32x4*)(p + 4);
        arg[2] = *(const f32x4*)(p + 8);
        arg[3] = *(const f32x4*)(p + 12);
        const u16x8* q = (const u16x8*)(bptr + kb);
        brg[0] = q[0]; brg[1] = q[1]; brg[2] = q[2]; brg[3] = q[3];
    };
    auto write_tile = [&](int buf) {
        u16x8 t0, t1;
#pragma unroll
        for (int i = 0; i < 4; ++i) {
            t0[i]     = f2bf(arg[0][i]);
            t0[i + 4] = f2bf(arg[1][i]);
            t1[i]     = f2bf(arg[2][i]);
            t1[i + 4] = f2bf(arg[3][i]);
        }
        u16x8* wa = (u16x8*)&lds_a[buf][ar * APAD + ak];
        wa[0] = t0; wa[1] = t1;
        u16x8* wb = (u16x8*)&lds_b[buf][tid * BPAD];
        wb[0] = brg[0]; wb[1] = brg[1]; wb[2] = brg[2]; wb[3] = brg[3];
    };

    f32x4 acc[4][8] = {};
    const int la = lane & 15;
    const int lg = lane >> 4;

    load_tile(0);
    write_tile(0);
    __syncthreads();
    int cur = 0;

    for (int t = 0; t < CDIM / BK; ++t) {
        if (t + 1 < CDIM / BK) load_tile((t + 1) * BK);

        const unsigned short* pa = &lds_a[cur][(wm * 64 + la) * APAD + lg * 8];
        const unsigned short* pb = &lds_b[cur][(wn * 128 + la) * BPAD + lg * 8];
        short8 af[4];
#pragma unroll
        for (int mi = 0; mi < 4; ++mi)
            af[mi] = *(const short8*)(pa + mi * 16 * APAD);
#pragma unroll
        for (int ni = 0; ni < 8; ++ni) {
            const short8 bf = *(const short8*)(pb + ni * 16 * BPAD);
#pragma unroll
            for (int mi = 0; mi < 4; ++mi)
                acc[mi][ni] = __builtin_amdgcn_mfma_f32_16x16x32_bf16(af[mi], bf, acc[mi][ni], 0, 0, 0);
        }

        if (t + 1 < CDIM / BK) write_tile(cur ^ 1);
        __syncthreads();
        cur ^= 1;
    }

    float bvr[8];
#pragma unroll
    for (int ni = 0; ni < 8; ++ni) bvr[ni] = bv[wn * 128 + ni * 16 + la];
#pragma unroll
    for (int mi = 0; mi < 4; ++mi) {
#pragma unroll
        for (int ni = 0; ni < 8; ++ni) {
            const int col = wn * 128 + ni * 16 + la;
#pragma unroll
            for (int j = 0; j < 4; ++j) {
                const long r = row0 + wm * 64 + mi * 16 + lg * 4 + j;
                vout[r * CDIM + col] = f2bf(acc[mi][ni][j] + bvr[ni]);
            }
        }
    }
}

// ---------------------------------------------------------------------------
// Kernel OA: offatt = query @ [Woff ; Watt] + bias  -> f32 [BS*LQ][288]
// BM=128, BN=288, BK=32, 4 waves (2x2), wave tile 64x144 (9 n-frags).
// ---------------------------------------------------------------------------
__global__ __launch_bounds__(256) void offatt_gemm_mfma(
    const float* __restrict__ query, const unsigned short* __restrict__ WoaT,
    const float* __restrict__ boff, const float* __restrict__ batt,
    float* __restrict__ offatt)
{
    __shared__ unsigned short lds_a[2][BM * APAD];
    __shared__ unsigned short lds_b[2][NOA * BPAD];

    const int tid = threadIdx.x;
    const int lane = tid & 63;
    const int wave = tid >> 6;
    const int wm = wave >> 1;
    const int wn = wave & 1;
    const long row0 = (long)blockIdx.x * BM;

    const int ar = tid >> 1;
    const int ak = (tid & 1) * 16;
    const float* aptr = query + (row0 + ar) * CDIM + ak;
    const unsigned short* bptr  = WoaT + (size_t)tid * CDIM;
    const unsigned short* bptr2 = WoaT + (size_t)(256 + tid) * CDIM;
    const bool extra = tid < 32;

    f32x4 arg[4];
    u16x8 brg[4], brg2[4];

    auto load_tile = [&](int kb) {
        const float* p = aptr + kb;
        arg[0] = *(const f32x4*)(p);
        arg[1] = *(const f32x4*)(p + 4);
        arg[2] = *(const f32x4*)(p + 8);
        arg[3] = *(const f32x4*)(p + 12);
        const u16x8* q = (const u16x8*)(bptr + kb);
        brg[0] = q[0]; brg[1] = q[1]; brg[2] = q[2]; brg[3] = q[3];
        if (extra) {
            const u16x8* q2 = (const u16x8*)(bptr2 + kb);
            brg2[0] = q2[0]; brg2[1] = q2[1]; brg2[2] = q2[2]; brg2[3] = q2[3];
        }
    };
    auto write_tile = [&](int buf) {
        u16x8 t0, t1;
#pragma unroll
        for (int i = 0; i < 4; ++i) {
            t0[i]     = f2bf(arg[0][i]);
            t0[i + 4] = f2bf(arg[1][i]);
            t1[i]     = f2bf(arg[2][i]);
            t1[i + 4] = f2bf(arg[3][i]);
        }
        u16x8* wa = (u16x8*)&lds_a[buf][ar * APAD + ak];
        wa[0] = t0; wa[1] = t1;
        u16x8* wb = (u16x8*)&lds_b[buf][tid * BPAD];
        wb[0] = brg[0]; wb[1] = brg[1]; wb[2] = brg[2]; wb[3] = brg[3];
        if (extra) {
            u16x8* wb2 = (u16x8*)&lds_b[buf][(256 + tid) * BPAD];
            wb2[0] = brg2[0]; wb2[1] = brg2[1]; wb2[2] = brg2[2]; wb2[3] = brg2[3];
        }
    };

    f32x4 acc[4][9] = {};
    const int la = lane & 15;
    const int lg = lane >> 4;

    load_tile(0);
    write_tile(0);
    __syncthreads();
    int cur = 0;

    for (int t = 0; t < CDIM / BK; ++t) {
        if (t + 1 < CDIM / BK) load_tile((t + 1) * BK);

        const unsigned short* pa = &lds_a[cur][(wm * 64 + la) * APAD + lg * 8];
        const unsigned short* pb = &lds_b[cur][(wn * 144 + la) * BPAD + lg * 8];
        short8 af[4];
#pragma unroll
        for (int mi = 0; mi < 4; ++mi)
            af[mi] = *(const short8*)(pa + mi * 16 * APAD);
#pragma unroll
        for (int ni = 0; ni < 9; ++ni) {
            const short8 bf = *(const short8*)(pb + ni * 16 * BPAD);
#pragma unroll
            for (int mi = 0; mi < 4; ++mi)
                acc[mi][ni] = __builtin_amdgcn_mfma_f32_16x16x32_bf16(af[mi], bf, acc[mi][ni], 0, 0, 0);
        }

        if (t + 1 < CDIM / BK) write_tile(cur ^ 1);
        __syncthreads();
        cur ^= 1;
    }

    float bias[9];
#pragma unroll
    for (int ni = 0; ni < 9; ++ni) {
        const int col = wn * 144 + ni * 16 + la;
        bias[ni] = (col < 192) ? boff[col] : batt[col - 192];
    }
#pragma unroll
    for (int mi = 0; mi < 4; ++mi) {
#pragma unroll
        for (int ni = 0; ni < 9; ++ni) {
            const int col = wn * 144 + ni * 16 + la;
#pragma unroll
            for (int j = 0; j < 4; ++j) {
                const long r = row0 + wm * 64 + mi * 16 + lg * 4 + j;
                offatt[r * NOA + col] = acc[mi][ni][j] + bias[ni];
            }
        }
    }
}

// ---------------------------------------------------------------------------
// Kernel B: softmax + locations + vectorized bilinear gather.
// One block per (b,q). thread = h*32 + pg*8 + d4: head h, point-group pg (3
// points each), dims 4*d4..4*d4+3 (ushort4 loads). Reduce over pg via shfl.
// Writes mid as bf16.
// ---------------------------------------------------------------------------
__global__ __launch_bounds__(256) void sample_kernel(
    const float* __restrict__ offatt, const float* __restrict__ refpts,
    const unsigned short* __restrict__ v, unsigned short* __restrict__ mid)
{
    __shared__ float oa_s[NOA];
    __shared__ float aw_s[96];
    __shared__ float px_s[96];
    __shared__ float py_s[96];

    const int tid = threadIdx.x;
    const int b = blockIdx.x / LQ;
    const int q = blockIdx.x % LQ;
    const long bq = (long)b * LQ + q;

    oa_s[tid] = offatt[bq * NOA + tid];
    if (tid < 32) oa_s[256 + tid] = offatt[bq * NOA + 256 + tid];
    __syncthreads();

    if (tid < 8) {
        float m = -1e30f;
#pragma unroll
        for (int i = 0; i < 12; ++i) m = fmaxf(m, oa_s[192 + tid * 12 + i]);
        float e[12];
        float s = 0.f;
#pragma unroll
        for (int i = 0; i < 12; ++i) { e[i] = __expf(oa_s[192 + tid * 12 + i] - m); s += e[i]; }
        const float inv = 1.f / s;
#pragma unroll
        for (int i = 0; i < 12; ++i) aw_s[tid * 12 + i] = e[i] * inv;
    }
    if (tid >= 128 && tid < 224) {
        const int t = tid - 128;
        const int h = t / 12, idx = t % 12, l = idx >> 2, p = idx & 3;
        const float* rp = refpts + (bq * NLEVELS + l) * 4;
        const float rx = rp[0], ry = rp[1], rw = rp[2], rh = rp[3];
        const float ox = oa_s[((h * NLEVELS + l) * NPOINTS + p) * 2 + 0];
        const float oy = oa_s[((h * NLEVELS + l) * NPOINTS + p) * 2 + 1];
        const float lx = rx + ox * 0.125f * rw;
        const float ly = ry + oy * 0.125f * rh;
        const int Wl = 80 >> l;
        px_s[t] = lx * (float)Wl - 0.5f;
        py_s[t] = ly * (float)Wl - 0.5f;
    }
    __syncthreads();

    const int h = tid >> 5;
    const int pg = (tid >> 3) & 3;
    const int d4 = tid & 7;
    const unsigned short* vb = v + ((size_t)b * LV) * CDIM + h * HD + d4 * 4;

    float a0 = 0.f, a1 = 0.f, a2 = 0.f, a3 = 0.f;
#pragma unroll
    for (int j = 0; j < 3; ++j) {
        const int i = pg * 3 + j;
        const int l = i >> 2;
        const int idx = h * 12 + i;
        const float px = px_s[idx], py = py_s[idx], aw = aw_s[idx];
        const int Wl = 80 >> l;
        const int start = (l == 0) ? 0 : (l == 1) ? 6400 : 8000;

        const float fx = floorf(px), fy = floorf(py);
        const int x0 = (int)fx, y0 = (int)fy;
        const float wx1 = px - fx, wy1 = py - fy;
        const float wx0 = 1.f - wx1, wy0 = 1.f - wy1;
        const float w00 = wx0 * wy0 * aw, w10 = wx1 * wy0 * aw;
        const float w01 = wx0 * wy1 * aw, w11 = wx1 * wy1 * aw;
        const bool x0v = (unsigned)x0 < (unsigned)Wl;
        const bool x1v = (unsigned)(x0 + 1) < (unsigned)Wl;
        const bool y0v = (unsigned)y0 < (unsigned)Wl;
        const bool y1v = (unsigned)(y0 + 1) < (unsigned)Wl;

        const unsigned short* base = vb + (size_t)start * CDIM;
        if (y0v) {
            const unsigned short* r0p = base + (size_t)(y0 * Wl) * CDIM;
            if (x0v) {
                const u16x4 u = *(const u16x4*)(r0p + (size_t)x0 * CDIM);
                a0 = fmaf(w00, bf2f(u[0]), a0); a1 = fmaf(w00, bf2f(u[1]), a1);
                a2 = fmaf(w00, bf2f(u[2]), a2); a3 = fmaf(w00, bf2f(u[3]), a3);
            }
            if (x1v) {
                const u16x4 u = *(const u16x4*)(r0p + (size_t)(x0 + 1) * CDIM);
                a0 = fmaf(w10, bf2f(u[0]), a0); a1 = fmaf(w10, bf2f(u[1]), a1);
                a2 = fmaf(w10, bf2f(u[2]), a2); a3 = fmaf(w10, bf2f(u[3]), a3);
            }
        }
        if (y1v) {
            const unsigned short* r1p = base + (size_t)((y0 + 1) * Wl) * CDIM;
            if (x0v) {
                const u16x4 u = *(const u16x4*)(r1p + (size_t)x0 * CDIM);
                a0 = fmaf(w01, bf2f(u[0]), a0); a1 = fmaf(w01, bf2f(u[1]), a1);
                a2 = fmaf(w01, bf2f(u[2]), a2); a3 = fmaf(w01, bf2f(u[3]), a3);
            }
            if (x1v) {
                const u16x4 u = *(const u16x4*)(r1p + (size_t)(x0 + 1) * CDIM);
                a0 = fmaf(w11, bf2f(u[0]), a0); a1 = fmaf(w11, bf2f(u[1]), a1);
                a2 = fmaf(w11, bf2f(u[2]), a2); a3 = fmaf(w11, bf2f(u[3]), a3);
            }
        }
    }

    a0 += __shfl_xor(a0, 8);  a1 += __shfl_xor(a1, 8);
    a2 += __shfl_xor(a2, 8);  a3 += __shfl_xor(a3, 8);
    a0 += __shfl_xor(a0, 16); a1 += __shfl_xor(a1, 16);
    a2 += __shfl_xor(a2, 16); a3 += __shfl_xor(a3, 16);

    if (pg == 0) {
        u16x4 o;
        o[0] = f2bf(a0); o[1] = f2bf(a1); o[2] = f2bf(a2); o[3] = f2bf(a3);
        *(u16x4*)&mid[bq * CDIM + h * HD + d4 * 4] = o;
    }
}

// ---------------------------------------------------------------------------
// Kernel C: out = mid(bf16) @ Wout + bout  via MFMA -> f32
// BM=128, BN=256, BK=32, 4 waves (2x2).
// ---------------------------------------------------------------------------
__global__ __launch_bounds__(256) void out_gemm_mfma(
    const unsigned short* __restrict__ mid, const unsigned short* __restrict__ WoutT,
    const float* __restrict__ bout, float* __restrict__ out)
{
    __shared__ unsigned short lds_a[2][BM * APAD];
    __shared__ unsigned short lds_b[2][256 * BPAD];

    const int tid = threadIdx.x;
    const int lane = tid & 63;
    const int wave = tid >> 6;
    const int wm = wave >> 1;
    const int wn = wave & 1;
    const long row0 = (long)blockIdx.x * BM;

    const int ar = tid >> 1;
    const int ak = (tid & 1) * 16;
    const unsigned short* aptr = mid + (row0 + ar) * CDIM + ak;
    const unsigned short* bptr = WoutT + (size_t)tid * CDIM;

    u16x8 arg[2];
    u16x8 brg[4];

    auto load_tile = [&](int kb) {
        const u16x8* p = (const u16x8*)(aptr + kb);
        arg[0] = p[0]; arg[1] = p[1];
        const u16x8* qq = (const u16x8*)(bptr + kb);
        brg[0] = qq[0]; brg[1] = qq[1]; brg[2] = qq[2]; brg[3] = qq[3];
    };
    auto write_tile = [&](int buf) {
        u16x8* wa = (u16x8*)&lds_a[buf][ar * APAD + ak];
        wa[0] = arg[0]; wa[1] = arg[1];
        u16x8* wb = (u16x8*)&lds_b[buf][tid * BPAD];
        wb[0] = brg[0]; wb[1] = brg[1]; wb[2] = brg[2]; wb[3] = brg[3];
    };

    f32x4 acc[4][8] = {};
    const int la = lane & 15;
    const int lg = lane >> 4;

    load_tile(0);
    write_tile(0);
    __syncthreads();
    int cur = 0;

    for (int t = 0; t < CDIM / BK; ++t) {
        if (t + 1 < CDIM / BK) load_tile((t + 1) * BK);

        const unsigned short* pa = &lds_a[cur][(wm * 64 + la) * APAD + lg * 8];
        const unsigned short* pb = &lds_b[cur][(wn * 128 + la) * BPAD + lg * 8];
        short8 af[4];
#pragma unroll
        for (int mi = 0; mi < 4; ++mi)
            af[mi] = *(const short8*)(pa + mi * 16 * APAD);
#pragma unroll
        for (int ni = 0; ni < 8; ++ni) {
            const short8 bf = *(const short8*)(pb + ni * 16 * BPAD);
#pragma unroll
            for (int mi = 0; mi < 4; ++mi)
                acc[mi][ni] = __builtin_amdgcn_mfma_f32_16x16x32_bf16(af[mi], bf, acc[mi][ni], 0, 0, 0);
        }

        if (t + 1 < CDIM / BK) write_tile(cur ^ 1);
        __syncthreads();
        cur ^= 1;
    }

    float br[8];
#pragma unroll
    for (int ni = 0; ni < 8; ++ni) br[ni] = bout[wn * 128 + ni * 16 + la];
#pragma unroll
    for (int mi = 0; mi < 4; ++mi) {
#pragma unroll
        for (int ni = 0; ni < 8; ++ni) {
            const int col = wn * 128 + ni * 16 + la;
#pragma unroll
            for (int j = 0; j < 4; ++j) {
                const long r = row0 + wm * 64 + mi * 16 + lg * 4 + j;
                out[r * CDIM + col] = acc[mi][ni][j] + br[ni];
            }
        }
    }
}

extern "C" void kernel_launch(void* const* d_in, const int* in_sizes, int n_in,
                              void* d_out, int out_size, void* d_ws, size_t ws_size,
                              hipStream_t stream) {
    const float* query = (const float*)d_in[0];
    const float* refp  = (const float*)d_in[1];
    const float* value = (const float*)d_in[2];
    const float* Wv    = (const float*)d_in[3];
    const float* bv    = (const float*)d_in[4];
    const float* Woff  = (const float*)d_in[5];
    const float* boff  = (const float*)d_in[6];
    const float* Watt  = (const float*)d_in[7];
    const float* batt  = (const float*)d_in[8];
    const float* Wout  = (const float*)d_in[9];
    const float* bout  = (const float*)d_in[10];
    float* out = (float*)d_out;

    char* ws = (char*)d_ws;
    unsigned short* v = (unsigned short*)ws;                        // bf16 [BS*LV][256]
    size_t off = (size_t)BS * LV * CDIM * 2;                        // 137,625,600
    float* offatt = (float*)(ws + off);                             // f32 [9600][288]
    off += (size_t)BS * LQ * NOA * 4;                               // +11,059,200
    unsigned short* mid = (unsigned short*)(ws + off);              // bf16 [9600][256]
    off += (size_t)BS * LQ * CDIM * 2;                              // +4,915,200
    unsigned short* WvT = (unsigned short*)(ws + off);
    off += 256 * 256 * 2;
    unsigned short* WoaT = (unsigned short*)(ws + off);
    off += NOA * 256 * 2;
    unsigned short* WoutT = (unsigned short*)(ws + off);

    transpose_w_kernel<<<256, 256, 0, stream>>>(Wv, WvT);
    transpose_w_kernel<<<256, 256, 0, stream>>>(Wout, WoutT);
    prep_woat_kernel<<<NOA, 256, 0, stream>>>(Woff, Watt, WoaT);

    proj_value_mfma<<<(BS * LV) / BM, 256, 0, stream>>>(value, WvT, bv, v);
    offatt_gemm_mfma<<<(BS * LQ) / BM, 256, 0, stream>>>(query, WoaT, boff, batt, offatt);
    sample_kernel<<<BS * LQ, 256, 0, stream>>>(offatt, refp, v, mid);
    out_gemm_mfma<<<(BS * LQ) / BM, 256, 0, stream>>>(mid, WoutT, bout, out);
}